// Round 3
// baseline (7590.694 us; speedup 1.0000x reference)
//
#include <hip/hip_runtime.h>
#include <hip/hip_bf16.h>

// P4Transformer forward, fp32 baseline.
// B=2, T=8, N=2048, M=256, Tq=4, JN=17, S=17+1024=1041, DIM=1024, HEADS=8, DHEAD=128
#define S_LEN 1041
#define ROWS  2082            // B * S_LEN

// Exact-match distance: mul + fma + fma, matching presumed XLA codegen for
// sum((a-b)**2, -1) over a minor axis of 3. Discrete decisions (argmax, radius
// membership) depend on bit-exactness with the JAX reference.
__device__ __forceinline__ float d2chain(float dx, float dy, float dz) {
  float t = dx * dx;
  t = fmaf(dy, dy, t);
  t = fmaf(dz, dz, t);
  return t;
}

__device__ __forceinline__ float gelu_exact(float v) {
  return 0.5f * v * (1.0f + erff(v * 0.70710678118654752f));
}

// ---------------------------------------------------------------- FPS
// One block per (b, tq) frame (8 blocks). Serial 255-iteration farthest-point
// sampling with block-wide argmax (tie-break: lowest index, matching jnp.argmax).
__global__ __launch_bounds__(256) void fps_kernel(const float* __restrict__ radar,
                                                  float* __restrict__ anchors,
                                                  float* __restrict__ xyzts) {
  __shared__ float xs[2048], ys[2048], zs[2048];
  __shared__ int warr[256];
  __shared__ float rv[4];
  __shared__ int ri[4];
  int bf = blockIdx.x;              // b*4 + tq
  int b = bf >> 2, tq = bf & 3;
  int f = 2 * tq;                   // centers[tq]-1 = 2*tq
  const float* base = radar + (size_t)(b * 8 + f) * 2048 * 6;
  int tid = threadIdx.x;
#pragma unroll
  for (int r = 0; r < 8; ++r) {
    int n = tid + r * 256;
    const float* p = base + (size_t)n * 6;
    xs[n] = p[0]; ys[n] = p[1]; zs[n] = p[2];
  }
  float dist[8];
#pragma unroll
  for (int r = 0; r < 8; ++r) dist[r] = 1e10f;
  if (tid == 0) warr[0] = 0;
  __syncthreads();
  int last = 0;
  for (int it = 1; it < 256; ++it) {
    float px = xs[last], py = ys[last], pz = zs[last];
    float bv = -1.0f; int bi = 0x7fffffff;
#pragma unroll
    for (int r = 0; r < 8; ++r) {
      int n = tid + r * 256;
      float d = fminf(dist[r], d2chain(xs[n] - px, ys[n] - py, zs[n] - pz));
      dist[r] = d;
      if (d > bv || (d == bv && n < bi)) { bv = d; bi = n; }
    }
#pragma unroll
    for (int o = 1; o < 64; o <<= 1) {
      float ov = __shfl_xor(bv, o);
      int   oi = __shfl_xor(bi, o);
      if (ov > bv || (ov == bv && oi < bi)) { bv = ov; bi = oi; }
    }
    if ((tid & 63) == 0) { rv[tid >> 6] = bv; ri[tid >> 6] = bi; }
    __syncthreads();
    if (tid == 0) {
      float fv = rv[0]; int fi = ri[0];
      for (int w = 1; w < 4; ++w)
        if (rv[w] > fv || (rv[w] == fv && ri[w] < fi)) { fv = rv[w]; fi = ri[w]; }
      warr[it] = fi;
    }
    __syncthreads();
    last = warr[it];
  }
  // gather anchors + emit xyzts output
  int m = tid;                      // 256 threads -> 256 anchors
  int a = warr[m];
  float ax = xs[a], ay = ys[a], az = zs[a];
  float* ap = anchors + (size_t)(bf * 256 + m) * 3;
  ap[0] = ax; ap[1] = ay; ap[2] = az;
  float* xp = xyzts + (size_t)(b * 1024 + tq * 256 + m) * 4;
  xp[0] = ax; xp[1] = ay; xp[2] = az; xp[3] = (float)(tq + 1);
}

// ---------------------------------------------------------- radius query
// One thread per (b,tq,o,m) row: first 16 indices (ascending) with d2 < 0.49.
__global__ __launch_bounds__(256) void radius_kernel(const float* __restrict__ radar,
                                                     const float* __restrict__ anchors,
                                                     int* __restrict__ nidx) {
  int r = blockIdx.x * 256 + threadIdx.x;   // ((b*4+tq)*3+o)*256+m ; 6144 total
  int m = r & 255;
  int g = r >> 8;
  int o = g % 3;
  int bt = g / 3;                 // b*4+tq
  int tq = bt & 3, b = bt >> 2;
  const float* ap = anchors + (size_t)(bt * 256 + m) * 3;
  float ax = ap[0], ay = ap[1], az = ap[2];
  int u = 2 * tq + o;             // centers[tq] + (o-1)
  int f = (u == 0) ? 0 : (u - 1);
  const float* base = radar + (size_t)(b * 8 + f) * 2048 * 6;
  size_t ob = (size_t)r * 16;
  int cnt = 0, first = 0;
  for (int n = 0; n < 2048; ++n) {
    const float* p = base + (size_t)n * 6;
    float t = d2chain(ax - p[0], ay - p[1], az - p[2]);
    if (t < 0.49f) {              // RADIUS**2 compared in fp32 (0.49f)
      if (cnt == 0) first = n;
      nidx[ob + cnt] = n;
      if (++cnt == 16) break;
    }
  }
  for (int k = cnt; k < 16; ++k) nidx[ob + k] = first;   // first==0 if cnt==0
}

// --------------------------------------------- grouping + pointconv + emb
// One block per (b,tq,m). 48 candidates (3 offsets x 16), 7-dim input each,
// conv to 1024 dims with max over the 48; also writes emb rows of x.
__global__ __launch_bounds__(256) void group_kernel(const float* __restrict__ radar,
                                                    const float* __restrict__ anchors,
                                                    const int* __restrict__ nidx,
                                                    const float* __restrict__ cdw,
                                                    const float* __restrict__ cfw,
                                                    const float* __restrict__ posw,
                                                    const float* __restrict__ posb,
                                                    float* __restrict__ feat,
                                                    float* __restrict__ x) {
  __shared__ float in7[48][8];
  int blk = blockIdx.x;           // b*1024 + tq*256 + m
  int m = blk & 255, bt = blk >> 8;
  int tq = bt & 3, b = bt >> 2;
  int tid = threadIdx.x;
  float a0 = anchors[(size_t)blk * 3 + 0];
  float a1 = anchors[(size_t)blk * 3 + 1];
  float a2 = anchors[(size_t)blk * 3 + 2];
  if (tid < 48) {
    int o = tid >> 4;
    int k = tid & 15;
    int gi = nidx[((size_t)(bt * 3 + o) * 256 + m) * 16 + k];
    int u = 2 * tq + o;
    int f = (u == 0) ? 0 : (u - 1);
    const float* p = radar + ((size_t)(b * 8 + f) * 2048 + gi) * 6;
    in7[tid][0] = p[0] - a0;
    in7[tid][1] = p[1] - a1;
    in7[tid][2] = p[2] - a2;
    in7[tid][3] = (float)(o - 1);
    in7[tid][4] = p[3];
    in7[tid][5] = p[4];
    in7[tid][6] = p[5];
  }
  __syncthreads();
  float tt = (float)(tq + 1);
#pragma unroll
  for (int j = 0; j < 4; ++j) {
    int d = j * 256 + tid;
    float4 wd = *(const float4*)(cdw + (size_t)d * 4);
    float w4 = cfw[(size_t)d * 3 + 0];
    float w5 = cfw[(size_t)d * 3 + 1];
    float w6 = cfw[(size_t)d * 3 + 2];
    float best = -INFINITY;
    for (int c = 0; c < 48; ++c) {
      const float* e = in7[c];
      float t = e[0] * wd.x;
      t = fmaf(e[1], wd.y, t);
      t = fmaf(e[2], wd.z, t);
      t = fmaf(e[3], wd.w, t);
      t = fmaf(e[4], w4, t);
      t = fmaf(e[5], w5, t);
      t = fmaf(e[6], w6, t);
      best = fmaxf(best, t);
    }
    feat[(size_t)blk * 1024 + d] = best;
    float4 pw = *(const float4*)(posw + (size_t)d * 4);
    float e = fmaf(a0, pw.x, fmaf(a1, pw.y, fmaf(a2, pw.z, fmaf(tt, pw.w, posb[d]))));
    x[((size_t)(b * 1041 + 17) + tq * 256 + m) * 1024 + d] = e + best;
  }
}

// ------------------------------------------------------------- joints rows
__global__ __launch_bounds__(256) void joints_kernel(const float* __restrict__ jt,
                                                     const float* __restrict__ jp,
                                                     float* __restrict__ x) {
  int blk = blockIdx.x;           // b*17 + j  (34 blocks)
  int b = blk / 17, jj = blk % 17;
  int d = threadIdx.x * 4;
  float4 t = *(const float4*)(jt + (size_t)jj * 1024 + d);
  float4 p = *(const float4*)(jp + (size_t)jj * 1024 + d);
  float4 r;
  r.x = t.x + p.x; r.y = t.y + p.y; r.z = t.z + p.z; r.w = t.w + p.w;
  *(float4*)(x + ((size_t)(b * 1041 + jj)) * 1024 + d) = r;
}

// ---------------------------------------------------------------- LayerNorm
__global__ __launch_bounds__(256) void ln_kernel(const float* __restrict__ x,
                                                 const float* __restrict__ s,
                                                 const float* __restrict__ b,
                                                 float* __restrict__ h) {
  __shared__ float red[8];
  int row = blockIdx.x;
  int tid = threadIdx.x;
  float4 v = *(const float4*)(x + (size_t)row * 1024 + tid * 4);
  float sum = (v.x + v.y) + (v.z + v.w);
#pragma unroll
  for (int o = 32; o > 0; o >>= 1) sum += __shfl_xor(sum, o);
  if ((tid & 63) == 0) red[tid >> 6] = sum;
  __syncthreads();
  float mean = (red[0] + red[1] + red[2] + red[3]) * (1.0f / 1024.0f);
  float dx = v.x - mean, dy = v.y - mean, dz = v.z - mean, dw = v.w - mean;
  float sq = (dx * dx + dy * dy) + (dz * dz + dw * dw);
#pragma unroll
  for (int o = 32; o > 0; o >>= 1) sq += __shfl_xor(sq, o);
  if ((tid & 63) == 0) red[4 + (tid >> 6)] = sq;
  __syncthreads();
  float var = (red[4] + red[5] + red[6] + red[7]) * (1.0f / 1024.0f);
  float rs = rsqrtf(var + 1e-5f);
  float4 sv = *(const float4*)(s + tid * 4);
  float4 bv = *(const float4*)(b + tid * 4);
  float4 out;
  out.x = dx * rs * sv.x + bv.x;
  out.y = dy * rs * sv.y + bv.y;
  out.z = dz * rs * sv.z + bv.z;
  out.w = dw * rs * sv.w + bv.w;
  *(float4*)(h + (size_t)row * 1024 + tid * 4) = out;
}

// ------------------------------------------------------------------- GEMM
// C[M,N] = A[M,K] @ B[K,N] (+bias) (+gelu) (+residual into C). Tile 64x128,
// 256 threads, 4x8 micro-tile, BK=16. fp32 vector-ALU (no fp32 MFMA on CDNA4).
template <bool BIAS, bool RES, bool GACT>
__global__ __launch_bounds__(256) void gemm64(const float* __restrict__ A,
                                              const float* __restrict__ Bw,
                                              const float* __restrict__ bias,
                                              float* __restrict__ C,
                                              int M, int N, int K) {
  __shared__ float As[16][68];
  __shared__ float Bs[16][132];
  int tid = threadIdx.x;
  int tx = tid & 15, ty = tid >> 4;
  int m0 = blockIdx.y * 64, n0 = blockIdx.x * 128;
  float acc[4][8] = {};
  int arow = tid >> 2, ak = (tid & 3) * 4;
  int brow = tid >> 4, bcol = (tid & 15) * 8;
  bool aok = (m0 + arow) < M;
  const float* aptr = A + (size_t)(m0 + arow) * K + ak;
  const float* bptr = Bw + (size_t)brow * N + n0 + bcol;
  for (int k0 = 0; k0 < K; k0 += 16) {
    float4 av = aok ? *(const float4*)(aptr + k0) : make_float4(0.f, 0.f, 0.f, 0.f);
    float4 b0 = *(const float4*)(bptr + (size_t)k0 * N);
    float4 b1 = *(const float4*)(bptr + (size_t)k0 * N + 4);
    __syncthreads();
    As[ak + 0][arow] = av.x;
    As[ak + 1][arow] = av.y;
    As[ak + 2][arow] = av.z;
    As[ak + 3][arow] = av.w;
    *(float4*)&Bs[brow][bcol] = b0;
    *(float4*)&Bs[brow][bcol + 4] = b1;
    __syncthreads();
#pragma unroll
    for (int kk = 0; kk < 16; ++kk) {
      float4 a4 = *(const float4*)&As[kk][ty * 4];
      float4 x0 = *(const float4*)&Bs[kk][tx * 8];
      float4 x1 = *(const float4*)&Bs[kk][tx * 8 + 4];
      float am[4] = {a4.x, a4.y, a4.z, a4.w};
      float bn[8] = {x0.x, x0.y, x0.z, x0.w, x1.x, x1.y, x1.z, x1.w};
#pragma unroll
      for (int i = 0; i < 4; ++i)
#pragma unroll
        for (int j = 0; j < 8; ++j) acc[i][j] = fmaf(am[i], bn[j], acc[i][j]);
    }
  }
#pragma unroll
  for (int i = 0; i < 4; ++i) {
    int row = m0 + ty * 4 + i;
    if (row < M) {
      float* cp = C + (size_t)row * N + n0 + tx * 8;
#pragma unroll
      for (int j = 0; j < 8; ++j) {
        float v = acc[i][j];
        if (BIAS) v += bias[n0 + tx * 8 + j];
        if (GACT) v = gelu_exact(v);
        if (RES) v += cp[j];
        cp[j] = v;
      }
    }
  }
}

// ------------------------------------------------------ flash attention fp32
// Block = (qblock of 32 queries) x (b,h). 8 lanes cooperate per query
// (16 dims each). K/V tiles of 32 keys staged in LDS; online softmax.
__global__ __launch_bounds__(256) void attn_kernel(const float* __restrict__ qkv,
                                                   float* __restrict__ o) {
  __shared__ float Ks[32][128];
  __shared__ float Vs[32][128];
  __shared__ float Sl[32][33];
  int bh = blockIdx.y;
  int b = bh >> 3, hh = bh & 7;
  int tid = threadIdx.x;
  int g = tid >> 3, l8 = tid & 7;
  int qi = blockIdx.x * 32 + g;
  bool qok = qi < S_LEN;
  const float* base = qkv + (size_t)b * S_LEN * 3072;
  float qv[16];
  if (qok) {
    const float4* qp = (const float4*)(base + (size_t)qi * 3072 + hh * 128 + l8 * 16);
    float4 q0 = qp[0], q1 = qp[1], q2 = qp[2], q3 = qp[3];
    qv[0] = q0.x; qv[1] = q0.y; qv[2] = q0.z; qv[3] = q0.w;
    qv[4] = q1.x; qv[5] = q1.y; qv[6] = q1.z; qv[7] = q1.w;
    qv[8] = q2.x; qv[9] = q2.y; qv[10] = q2.z; qv[11] = q2.w;
    qv[12] = q3.x; qv[13] = q3.y; qv[14] = q3.z; qv[15] = q3.w;
  } else {
#pragma unroll
    for (int j = 0; j < 16; ++j) qv[j] = 0.f;
  }
  float ov[16];
#pragma unroll
  for (int j = 0; j < 16; ++j) ov[j] = 0.f;
  float mrun = -INFINITY, lrun = 0.f;
  const float scale = 0.08838834764831845f;   // DHEAD**-0.5
  for (int j0 = 0; j0 < S_LEN; j0 += 32) {
    __syncthreads();
#pragma unroll
    for (int r = 0; r < 4; ++r) {
      int f4 = r * 256 + tid;
      int key = f4 >> 5;
      int c4 = (f4 & 31) * 4;
      int jj = j0 + key;
      float4 kv, vv;
      if (jj < S_LEN) {
        kv = *(const float4*)(base + (size_t)jj * 3072 + 1024 + hh * 128 + c4);
        vv = *(const float4*)(base + (size_t)jj * 3072 + 2048 + hh * 128 + c4);
      } else {
        kv = make_float4(0.f, 0.f, 0.f, 0.f);
        vv = make_float4(0.f, 0.f, 0.f, 0.f);
      }
      *(float4*)&Ks[key][c4] = kv;
      *(float4*)&Vs[key][c4] = vv;
    }
    __syncthreads();
    float tmax = -INFINITY;
    for (int jj = 0; jj < 32; ++jj) {
      const float* kr = &Ks[jj][l8 * 16];
      float4 k0 = *(const float4*)(kr);
      float4 k1 = *(const float4*)(kr + 4);
      float4 k2 = *(const float4*)(kr + 8);
      float4 k3 = *(const float4*)(kr + 12);
      float s0 = qv[0] * k0.x; s0 = fmaf(qv[1], k0.y, s0); s0 = fmaf(qv[2], k0.z, s0); s0 = fmaf(qv[3], k0.w, s0);
      float s1 = qv[4] * k1.x; s1 = fmaf(qv[5], k1.y, s1); s1 = fmaf(qv[6], k1.z, s1); s1 = fmaf(qv[7], k1.w, s1);
      float s2 = qv[8] * k2.x; s2 = fmaf(qv[9], k2.y, s2); s2 = fmaf(qv[10], k2.z, s2); s2 = fmaf(qv[11], k2.w, s2);
      float s3 = qv[12] * k3.x; s3 = fmaf(qv[13], k3.y, s3); s3 = fmaf(qv[14], k3.z, s3); s3 = fmaf(qv[15], k3.w, s3);
      float s = (s0 + s1) + (s2 + s3);
      s += __shfl_xor(s, 1);
      s += __shfl_xor(s, 2);
      s += __shfl_xor(s, 4);
      s *= scale;
      if (j0 + jj >= S_LEN) s = -INFINITY;
      if (l8 == (jj & 7)) Sl[g][jj] = s;
      tmax = fmaxf(tmax, s);
    }
    __syncthreads();
    float mnew = fmaxf(mrun, tmax);
    float corr = expf(mrun - mnew);
    lrun *= corr;
#pragma unroll
    for (int j = 0; j < 16; ++j) ov[j] *= corr;
    for (int jj = 0; jj < 32; ++jj) {
      float p = expf(Sl[g][jj] - mnew);
      lrun += p;
      const float* vr = &Vs[jj][l8 * 16];
      float4 v0 = *(const float4*)(vr);
      float4 v1 = *(const float4*)(vr + 4);
      float4 v2 = *(const float4*)(vr + 8);
      float4 v3 = *(const float4*)(vr + 12);
      ov[0] = fmaf(p, v0.x, ov[0]);  ov[1] = fmaf(p, v0.y, ov[1]);
      ov[2] = fmaf(p, v0.z, ov[2]);  ov[3] = fmaf(p, v0.w, ov[3]);
      ov[4] = fmaf(p, v1.x, ov[4]);  ov[5] = fmaf(p, v1.y, ov[5]);
      ov[6] = fmaf(p, v1.z, ov[6]);  ov[7] = fmaf(p, v1.w, ov[7]);
      ov[8] = fmaf(p, v2.x, ov[8]);  ov[9] = fmaf(p, v2.y, ov[9]);
      ov[10] = fmaf(p, v2.z, ov[10]); ov[11] = fmaf(p, v2.w, ov[11]);
      ov[12] = fmaf(p, v3.x, ov[12]); ov[13] = fmaf(p, v3.y, ov[13]);
      ov[14] = fmaf(p, v3.z, ov[14]); ov[15] = fmaf(p, v3.w, ov[15]);
    }
    mrun = mnew;
  }
  if (qok) {
    float inv = 1.0f / lrun;
    float* op = o + ((size_t)(b * S_LEN + qi)) * 1024 + hh * 128 + l8 * 16;
#pragma unroll
    for (int j = 0; j < 16; ++j) op[j] = ov[j] * inv;
  }
}

// --------------------------------------------------- reduction head (j -> j64)
__global__ __launch_bounds__(256) void red_kernel(const float* __restrict__ x,
                                                  const float* __restrict__ lns,
                                                  const float* __restrict__ lnb,
                                                  const float* __restrict__ w1,
                                                  const float* __restrict__ b1,
                                                  const float* __restrict__ w2,
                                                  const float* __restrict__ b2,
                                                  float* __restrict__ j64) {
  __shared__ float row[1024];
  __shared__ float hid[512];
  __shared__ float red[8];
  int blk = blockIdx.x;           // b*17 + j
  int b = blk / 17, jj = blk % 17;
  int tid = threadIdx.x;
  float4 v = *(const float4*)(x + ((size_t)(b * 1041 + jj)) * 1024 + tid * 4);
  float sum = (v.x + v.y) + (v.z + v.w);
#pragma unroll
  for (int o = 32; o > 0; o >>= 1) sum += __shfl_xor(sum, o);
  if ((tid & 63) == 0) red[tid >> 6] = sum;
  __syncthreads();
  float mean = (red[0] + red[1] + red[2] + red[3]) * (1.0f / 1024.0f);
  float dx = v.x - mean, dy = v.y - mean, dz = v.z - mean, dw = v.w - mean;
  float sq = (dx * dx + dy * dy) + (dz * dz + dw * dw);
#pragma unroll
  for (int o = 32; o > 0; o >>= 1) sq += __shfl_xor(sq, o);
  if ((tid & 63) == 0) red[4 + (tid >> 6)] = sq;
  __syncthreads();
  float var = (red[4] + red[5] + red[6] + red[7]) * (1.0f / 1024.0f);
  float rs = rsqrtf(var + 1e-5f);
  float4 sv = *(const float4*)(lns + tid * 4);
  float4 bv = *(const float4*)(lnb + tid * 4);
  row[tid * 4 + 0] = dx * rs * sv.x + bv.x;
  row[tid * 4 + 1] = dy * rs * sv.y + bv.y;
  row[tid * 4 + 2] = dz * rs * sv.z + bv.z;
  row[tid * 4 + 3] = dw * rs * sv.w + bv.w;
  __syncthreads();
  for (int u = tid; u < 512; u += 256) {
    float acc = 0.f;
    for (int c = 0; c < 1024; ++c) acc = fmaf(row[c], w1[(size_t)c * 512 + u], acc);
    hid[u] = fmaxf(acc + b1[u], 0.f);
  }
  __syncthreads();
  if (tid < 64) {
    float acc = 0.f;
    for (int c = 0; c < 512; ++c) acc = fmaf(hid[c], w2[(size_t)c * 64 + tid], acc);
    j64[(size_t)blk * 64 + tid] = acc + b2[tid];
  }
}

// ------------------------------------------------------ final head (j64 -> 3)
__global__ __launch_bounds__(64) void head_kernel(const float* __restrict__ j64,
                                                  const float* __restrict__ lns,
                                                  const float* __restrict__ lnb,
                                                  const float* __restrict__ w1,
                                                  const float* __restrict__ b1,
                                                  const float* __restrict__ w2,
                                                  const float* __restrict__ b2,
                                                  float* __restrict__ outp) {
  __shared__ float nb[64];
  __shared__ float hid[32];
  int blk = blockIdx.x;           // b*17 + j (34 blocks), 64 threads
  int tid = threadIdx.x;
  float v = j64[(size_t)blk * 64 + tid];
  float sum = v;
#pragma unroll
  for (int o = 32; o > 0; o >>= 1) sum += __shfl_xor(sum, o);
  float mean = sum * (1.0f / 64.0f);
  float d = v - mean;
  float sq = d * d;
#pragma unroll
  for (int o = 32; o > 0; o >>= 1) sq += __shfl_xor(sq, o);
  float var = sq * (1.0f / 64.0f);
  float rs = rsqrtf(var + 1e-5f);
  nb[tid] = d * rs * lns[tid] + lnb[tid];
  __syncthreads();
  if (tid < 32) {
    float acc = 0.f;
    for (int c = 0; c < 64; ++c) acc = fmaf(nb[c], w1[c * 32 + tid], acc);
    hid[tid] = fmaxf(acc + b1[tid], 0.f);
  }
  __syncthreads();
  if (tid < 3) {
    float acc = 0.f;
    for (int c = 0; c < 32; ++c) acc = fmaf(hid[c], w2[c * 3 + tid], acc);
    outp[(size_t)blk * 3 + tid] = acc + b2[tid];
  }
}

extern "C" void kernel_launch(void* const* d_in, const int* in_sizes, int n_in,
                              void* d_out, int out_size, void* d_ws, size_t ws_size,
                              hipStream_t stream) {
  const float* radar = (const float*)d_in[0];
  const float* cdw   = (const float*)d_in[1];
  const float* cfw   = (const float*)d_in[2];
  const float* posw  = (const float*)d_in[3];
  const float* posb  = (const float*)d_in[4];
  const float* jt    = (const float*)d_in[5];
  const float* jp    = (const float*)d_in[6];
  const float* ln1s  = (const float*)d_in[7];
  const float* ln1b  = (const float*)d_in[8];
  const float* qkvw  = (const float*)d_in[9];
  const float* outw  = (const float*)d_in[10];
  const float* outb  = (const float*)d_in[11];
  const float* ln2s  = (const float*)d_in[12];
  const float* ln2b  = (const float*)d_in[13];
  const float* ffw1  = (const float*)d_in[14];
  const float* ffb1  = (const float*)d_in[15];
  const float* ffw2  = (const float*)d_in[16];
  const float* ffb2  = (const float*)d_in[17];
  const float* rlns  = (const float*)d_in[18];
  const float* rlnb  = (const float*)d_in[19];
  const float* rw1   = (const float*)d_in[20];
  const float* rb1   = (const float*)d_in[21];
  const float* rw2   = (const float*)d_in[22];
  const float* rb2   = (const float*)d_in[23];
  const float* hlns  = (const float*)d_in[24];
  const float* hlnb  = (const float*)d_in[25];
  const float* hw1   = (const float*)d_in[26];
  const float* hb1   = (const float*)d_in[27];
  const float* hw2   = (const float*)d_in[28];
  const float* hb2   = (const float*)d_in[29];

  // Output layout: out(102) | j64(2176) | features(2097152) | xyzts(8192)
  float* out0      = (float*)d_out;
  float* out_j64   = out0 + 102;
  float* out_feat  = out_j64 + 2176;
  float* out_xyzts = out_feat + 2097152;

  // Workspace carve (all fp32): anchors | nidx | x | h | big(qkv/ffh)
  float* anchors = (float*)d_ws;                                  // 6144 f
  int*   nidx    = (int*)((char*)d_ws + 6144 * 4);                // 98304 i
  float* xbuf    = (float*)((char*)d_ws + (6144 + 98304) * 4);    // 2082*1024
  float* hbuf    = xbuf + (size_t)ROWS * 1024;                    // 2082*1024
  float* big     = hbuf + (size_t)ROWS * 1024;                    // 2082*3072
  if (ws_size < 43057152u) return;   // 43.06 MB needed

  fps_kernel<<<8, 256, 0, stream>>>(radar, anchors, out_xyzts);
  radius_kernel<<<24, 256, 0, stream>>>(radar, anchors, nidx);
  group_kernel<<<2048, 256, 0, stream>>>(radar, anchors, nidx, cdw, cfw, posw, posb,
                                         out_feat, xbuf);
  joints_kernel<<<34, 256, 0, stream>>>(jt, jp, xbuf);

  for (int l = 0; l < 5; ++l) {
    ln_kernel<<<ROWS, 256, 0, stream>>>(xbuf, ln1s + l * 1024, ln1b + l * 1024, hbuf);
    gemm64<false, false, false><<<dim3(24, 33), 256, 0, stream>>>(
        hbuf, qkvw + (size_t)l * 1024 * 3072, nullptr, big, ROWS, 3072, 1024);
    attn_kernel<<<dim3(33, 16), 256, 0, stream>>>(big, hbuf);   // o -> hbuf
    gemm64<true, true, false><<<dim3(8, 33), 256, 0, stream>>>(
        hbuf, outw + (size_t)l * 1024 * 1024, outb + l * 1024, xbuf, ROWS, 1024, 1024);
    ln_kernel<<<ROWS, 256, 0, stream>>>(xbuf, ln2s + l * 1024, ln2b + l * 1024, hbuf);
    gemm64<true, false, true><<<dim3(16, 33), 256, 0, stream>>>(
        hbuf, ffw1 + (size_t)l * 1024 * 2048, ffb1 + l * 2048, big, ROWS, 2048, 1024);
    gemm64<true, true, false><<<dim3(8, 33), 256, 0, stream>>>(
        big, ffw2 + (size_t)l * 2048 * 1024, ffb2 + l * 1024, xbuf, ROWS, 1024, 2048);
  }

  red_kernel<<<34, 256, 0, stream>>>(xbuf, rlns, rlnb, rw1, rb1, rw2, rb2, out_j64);
  head_kernel<<<34, 64, 0, stream>>>(out_j64, hlns, hlnb, hw1, hb1, hw2, hb2, out0);
}

// Round 11
// 6733.200 us; speedup vs baseline: 1.1274x; 1.1274x over previous
//
#include <hip/hip_runtime.h>
#include <hip/hip_bf16.h>

// P4Transformer forward. Point-cloud pipeline exact fp32; transformer GEMMs in
// split-bf16 MFMA (3-product Ootomo scheme, fp32 accumulate); attention fp32
// with conflict-free LDS swizzle.
// B=2, T=8, N=2048, M=256, Tq=4, JN=17, S=17+1024=1041, DIM=1024
#define S_LEN 1041
#define ROWS  2082            // B * S_LEN

typedef __attribute__((ext_vector_type(8))) short bs8;    // 8 bf16 (4 VGPR)
typedef __attribute__((ext_vector_type(4))) float f32x4;  // MFMA acc

union U8 { bs8 v; unsigned short u[8]; uint4 q; };

__device__ __forceinline__ unsigned short f2bf(float x) {   // RNE fp32->bf16
  unsigned int u = __float_as_uint(x);
  return (unsigned short)((u + 0x7FFFu + ((u >> 16) & 1u)) >> 16);
}
__device__ __forceinline__ float bf2f(unsigned short h) {
  return __uint_as_float(((unsigned int)h) << 16);
}

__device__ __forceinline__ f32x4 mfma16(bs8 a, bs8 b, f32x4 c) {
  return __builtin_amdgcn_mfma_f32_16x16x32_bf16(a, b, c, 0, 0, 0);
}

__device__ __forceinline__ float d2chain(float dx, float dy, float dz) {
  float t = dx * dx;
  t = fmaf(dy, dy, t);
  t = fmaf(dz, dz, t);
  return t;
}

__device__ __forceinline__ float gelu_exact(float v) {
  return 0.5f * v * (1.0f + erff(v * 0.70710678118654752f));
}

// ---------------------------------------------------------------- FPS
__global__ __launch_bounds__(256) void fps_kernel(const float* __restrict__ radar,
                                                  float* __restrict__ anchors,
                                                  float* __restrict__ xyzts) {
  __shared__ float xs[2048], ys[2048], zs[2048];
  __shared__ int warr[256];
  __shared__ float rv[4];
  __shared__ int ri[4];
  int bf = blockIdx.x;              // b*4 + tq
  int b = bf >> 2, tq = bf & 3;
  int f = 2 * tq;
  const float* base = radar + (size_t)(b * 8 + f) * 2048 * 6;
  int tid = threadIdx.x;
#pragma unroll
  for (int r = 0; r < 8; ++r) {
    int n = tid + r * 256;
    const float* p = base + (size_t)n * 6;
    xs[n] = p[0]; ys[n] = p[1]; zs[n] = p[2];
  }
  float dist[8];
#pragma unroll
  for (int r = 0; r < 8; ++r) dist[r] = 1e10f;
  if (tid == 0) warr[0] = 0;
  __syncthreads();
  int last = 0;
  for (int it = 1; it < 256; ++it) {
    float px = xs[last], py = ys[last], pz = zs[last];
    float bv = -1.0f; int bi = 0x7fffffff;
#pragma unroll
    for (int r = 0; r < 8; ++r) {
      int n = tid + r * 256;
      float d = fminf(dist[r], d2chain(xs[n] - px, ys[n] - py, zs[n] - pz));
      dist[r] = d;
      if (d > bv || (d == bv && n < bi)) { bv = d; bi = n; }
    }
#pragma unroll
    for (int o = 1; o < 64; o <<= 1) {
      float ov = __shfl_xor(bv, o);
      int   oi = __shfl_xor(bi, o);
      if (ov > bv || (ov == bv && oi < bi)) { bv = ov; bi = oi; }
    }
    if ((tid & 63) == 0) { rv[tid >> 6] = bv; ri[tid >> 6] = bi; }
    __syncthreads();
    if (tid == 0) {
      float fv = rv[0]; int fi = ri[0];
      for (int w = 1; w < 4; ++w)
        if (rv[w] > fv || (rv[w] == fv && ri[w] < fi)) { fv = rv[w]; fi = ri[w]; }
      warr[it] = fi;
    }
    __syncthreads();
    last = warr[it];
  }
  int m = tid;
  int a = warr[m];
  float ax = xs[a], ay = ys[a], az = zs[a];
  float* ap = anchors + (size_t)(bf * 256 + m) * 3;
  ap[0] = ax; ap[1] = ay; ap[2] = az;
  float* xp = xyzts + (size_t)(b * 1024 + tq * 256 + m) * 4;
  xp[0] = ax; xp[1] = ay; xp[2] = az; xp[3] = (float)(tq + 1);
}

// ---------------------------------------------------------- radius query
__global__ __launch_bounds__(256) void radius_kernel(const float* __restrict__ radar,
                                                     const float* __restrict__ anchors,
                                                     int* __restrict__ nidx) {
  int r = blockIdx.x * 256 + threadIdx.x;
  int m = r & 255;
  int g = r >> 8;
  int o = g % 3;
  int bt = g / 3;
  int tq = bt & 3, b = bt >> 2;
  const float* ap = anchors + (size_t)(bt * 256 + m) * 3;
  float ax = ap[0], ay = ap[1], az = ap[2];
  int u = 2 * tq + o;
  int f = (u == 0) ? 0 : (u - 1);
  const float* base = radar + (size_t)(b * 8 + f) * 2048 * 6;
  size_t ob = (size_t)r * 16;
  int cnt = 0, first = 0;
  for (int n = 0; n < 2048; ++n) {
    const float* p = base + (size_t)n * 6;
    float t = d2chain(ax - p[0], ay - p[1], az - p[2]);
    if (t < 0.49f) {
      if (cnt == 0) first = n;
      nidx[ob + cnt] = n;
      if (++cnt == 16) break;
    }
  }
  for (int k = cnt; k < 16; ++k) nidx[ob + k] = first;
}

// --------------------------------------------- grouping + pointconv + emb
__global__ __launch_bounds__(256) void group_kernel(const float* __restrict__ radar,
                                                    const float* __restrict__ anchors,
                                                    const int* __restrict__ nidx,
                                                    const float* __restrict__ cdw,
                                                    const float* __restrict__ cfw,
                                                    const float* __restrict__ posw,
                                                    const float* __restrict__ posb,
                                                    float* __restrict__ feat,
                                                    float* __restrict__ x) {
  __shared__ float in7[48][8];
  int blk = blockIdx.x;
  int m = blk & 255, bt = blk >> 8;
  int tq = bt & 3, b = bt >> 2;
  int tid = threadIdx.x;
  float a0 = anchors[(size_t)blk * 3 + 0];
  float a1 = anchors[(size_t)blk * 3 + 1];
  float a2 = anchors[(size_t)blk * 3 + 2];
  if (tid < 48) {
    int o = tid >> 4;
    int k = tid & 15;
    int gi = nidx[((size_t)(bt * 3 + o) * 256 + m) * 16 + k];
    int u = 2 * tq + o;
    int f = (u == 0) ? 0 : (u - 1);
    const float* p = radar + ((size_t)(b * 8 + f) * 2048 + gi) * 6;
    in7[tid][0] = p[0] - a0;
    in7[tid][1] = p[1] - a1;
    in7[tid][2] = p[2] - a2;
    in7[tid][3] = (float)(o - 1);
    in7[tid][4] = p[3];
    in7[tid][5] = p[4];
    in7[tid][6] = p[5];
  }
  __syncthreads();
  float tt = (float)(tq + 1);
#pragma unroll
  for (int j = 0; j < 4; ++j) {
    int d = j * 256 + tid;
    float4 wd = *(const float4*)(cdw + (size_t)d * 4);
    float w4 = cfw[(size_t)d * 3 + 0];
    float w5 = cfw[(size_t)d * 3 + 1];
    float w6 = cfw[(size_t)d * 3 + 2];
    float best = -INFINITY;
    for (int c = 0; c < 48; ++c) {
      const float* e = in7[c];
      float t = e[0] * wd.x;
      t = fmaf(e[1], wd.y, t);
      t = fmaf(e[2], wd.z, t);
      t = fmaf(e[3], wd.w, t);
      t = fmaf(e[4], w4, t);
      t = fmaf(e[5], w5, t);
      t = fmaf(e[6], w6, t);
      best = fmaxf(best, t);
    }
    feat[(size_t)blk * 1024 + d] = best;
    float4 pw = *(const float4*)(posw + (size_t)d * 4);
    float e = fmaf(a0, pw.x, fmaf(a1, pw.y, fmaf(a2, pw.z, fmaf(tt, pw.w, posb[d]))));
    x[((size_t)(b * 1041 + 17) + tq * 256 + m) * 1024 + d] = e + best;
  }
}

// ------------------------------------------------------------- joints rows
__global__ __launch_bounds__(256) void joints_kernel(const float* __restrict__ jt,
                                                     const float* __restrict__ jp,
                                                     float* __restrict__ x) {
  int blk = blockIdx.x;
  int b = blk / 17, jj = blk % 17;
  int d = threadIdx.x * 4;
  float4 t = *(const float4*)(jt + (size_t)jj * 1024 + d);
  float4 p = *(const float4*)(jp + (size_t)jj * 1024 + d);
  float4 r;
  r.x = t.x + p.x; r.y = t.y + p.y; r.z = t.z + p.z; r.w = t.w + p.w;
  *(float4*)(x + ((size_t)(b * 1041 + jj)) * 1024 + d) = r;
}

// ---------------------------------------------------------------- LayerNorm
__global__ __launch_bounds__(256) void ln_kernel(const float* __restrict__ x,
                                                 const float* __restrict__ s,
                                                 const float* __restrict__ b,
                                                 float* __restrict__ h) {
  __shared__ float red[8];
  int row = blockIdx.x;
  int tid = threadIdx.x;
  float4 v = *(const float4*)(x + (size_t)row * 1024 + tid * 4);
  float sum = (v.x + v.y) + (v.z + v.w);
#pragma unroll
  for (int o = 32; o > 0; o >>= 1) sum += __shfl_xor(sum, o);
  if ((tid & 63) == 0) red[tid >> 6] = sum;
  __syncthreads();
  float mean = (red[0] + red[1] + red[2] + red[3]) * (1.0f / 1024.0f);
  float dx = v.x - mean, dy = v.y - mean, dz = v.z - mean, dw = v.w - mean;
  float sq = (dx * dx + dy * dy) + (dz * dz + dw * dw);
#pragma unroll
  for (int o = 32; o > 0; o >>= 1) sq += __shfl_xor(sq, o);
  if ((tid & 63) == 0) red[4 + (tid >> 6)] = sq;
  __syncthreads();
  float var = (red[4] + red[5] + red[6] + red[7]) * (1.0f / 1024.0f);
  float rs = rsqrtf(var + 1e-5f);
  float4 sv = *(const float4*)(s + tid * 4);
  float4 bv = *(const float4*)(b + tid * 4);
  float4 out;
  out.x = dx * rs * sv.x + bv.x;
  out.y = dy * rs * sv.y + bv.y;
  out.z = dz * rs * sv.z + bv.z;
  out.w = dw * rs * sv.w + bv.w;
  *(float4*)(h + (size_t)row * 1024 + tid * 4) = out;
}

// -------------------------------------------------- weight convert/transpose
// W [K][N] fp32 -> fragment-linear split-bf16: hi plane then lo plane, each
// laid out [nt=N/16][kb=K/32][lane=64][j=8] so the GEMM's B-frag is a single
// coalesced 16B read per lane. (B-frag: lane l = col l&15, k=(l>>4)*8+j.)
__global__ __launch_bounds__(256) void wconv(const float* __restrict__ W,
                                             unsigned short* __restrict__ out,
                                             int K, int N) {
  int tid = threadIdx.x;
  int l = tid & 63, w = tid >> 6;
  int kb = blockIdx.y;
  int K32 = K >> 5;
  size_t plane = (size_t)K * N;
#pragma unroll
  for (int t = 0; t < 2; ++t) {
    int nt = blockIdx.x * 8 + w * 2 + t;
    int col = nt * 16 + (l & 15);
    int krow = kb * 32 + ((l >> 4) << 3);
    U8 h, lo;
#pragma unroll
    for (int j = 0; j < 8; ++j) {
      float xv = W[(size_t)(krow + j) * N + col];
      unsigned short hb = f2bf(xv);
      h.u[j] = hb;
      lo.u[j] = f2bf(xv - bf2f(hb));
    }
    size_t idx = (((size_t)nt * K32 + kb) * 64 + l) * 8;
    *(uint4*)(out + idx) = h.q;
    *(uint4*)(out + plane + idx) = lo.q;
  }
}

// ------------------------------------------------------- MFMA GEMM (split bf16)
// C[M,N] = A[M,K] @ W[K,N] via 3 MFMA products (AhBh + AlBh + AhBl), fp32 acc.
// A fp32 row-major converted during LDS staging; W from wconv fragment buffer.
// Tile 128x128, BK=32, 256 threads = 4 waves, wave tile 64x64 (4x4 16x16 frags).
template <bool BIAS, bool RES, bool GACT>
__global__ __launch_bounds__(256) void mgemm(const float* __restrict__ A,
                                             const unsigned short* __restrict__ Wf,
                                             const float* __restrict__ bias,
                                             float* __restrict__ C,
                                             int M, int N, int K) {
  __shared__ uint4 sA[2][8][64];   // [hi/lo][m-tile][lane] 16KB
  __shared__ uint4 sB[2][8][64];   // [hi/lo][n-tile][lane] 16KB
  int tid = threadIdx.x;
  int l = tid & 63, w = tid >> 6;
  int wm = w >> 1, wn = w & 1;     // wave -> 64x64 quadrant
  int m0 = blockIdx.y * 128, n0 = blockIdx.x * 128;
  int K32 = K >> 5;
  size_t plane = (size_t)K * N;
  f32x4 acc[4][4] = {};
  for (int k0 = 0; k0 < K32; ++k0) {
    // ---- stage A (convert fp32 -> hi/lo bf16, fragment order). wave w: mt = w, w+4
#pragma unroll
    for (int s = 0; s < 2; ++s) {
      int mt = w + s * 4;
      int row = m0 + mt * 16 + (l & 15);
      int kb = (k0 << 5) + ((l >> 4) << 3);
      float v[8];
      if (row < M) {
        float4 p0 = *(const float4*)(A + (size_t)row * K + kb);
        float4 p1 = *(const float4*)(A + (size_t)row * K + kb + 4);
        v[0] = p0.x; v[1] = p0.y; v[2] = p0.z; v[3] = p0.w;
        v[4] = p1.x; v[5] = p1.y; v[6] = p1.z; v[7] = p1.w;
      } else {
#pragma unroll
        for (int j = 0; j < 8; ++j) v[j] = 0.f;
      }
      U8 h, lo;
#pragma unroll
      for (int j = 0; j < 8; ++j) {
        unsigned short hb = f2bf(v[j]);
        h.u[j] = hb;
        lo.u[j] = f2bf(v[j] - bf2f(hb));
      }
      sA[0][mt][l] = h.q;
      sA[1][mt][l] = lo.q;
    }
    // ---- stage B (already fragment-linear in global). 16 segs / 4 waves.
#pragma unroll
    for (int s2 = 0; s2 < 4; ++s2) {
      int seg = w * 4 + s2;
      int ntl = seg >> 1, ver = seg & 1;
      int ntg = (n0 >> 4) + ntl;
      size_t gidx = (((size_t)ntg * K32 + k0) * 64 + l) * 8 + (ver ? plane : 0);
      sB[ver][ntl][l] = *(const uint4*)(Wf + gidx);
    }
    __syncthreads();
    U8 ah[4], al[4], bh[4], bl[4];
#pragma unroll
    for (int i = 0; i < 4; ++i) {
      ah[i].q = sA[0][wm * 4 + i][l];
      al[i].q = sA[1][wm * 4 + i][l];
      bh[i].q = sB[0][wn * 4 + i][l];
      bl[i].q = sB[1][wn * 4 + i][l];
    }
#pragma unroll
    for (int i = 0; i < 4; ++i)
#pragma unroll
      for (int j = 0; j < 4; ++j) {
        acc[i][j] = mfma16(ah[i].v, bh[j].v, acc[i][j]);
        acc[i][j] = mfma16(al[i].v, bh[j].v, acc[i][j]);
        acc[i][j] = mfma16(ah[i].v, bl[j].v, acc[i][j]);
      }
    __syncthreads();
  }
  // ---- epilogue. C/D: col = lane&15, row = (lane>>4)*4 + reg  [m89/m91]
#pragma unroll
  for (int i = 0; i < 4; ++i) {
    int rbase = m0 + wm * 64 + i * 16 + ((l >> 4) << 2);
#pragma unroll
    for (int j = 0; j < 4; ++j) {
      int col = n0 + wn * 64 + j * 16 + (l & 15);
      f32x4 c = acc[i][j];
#pragma unroll
      for (int reg = 0; reg < 4; ++reg) {
        int row = rbase + reg;
        if (row < M) {
          float v = c[reg];
          if (BIAS) v += bias[col];
          if (GACT) v = gelu_exact(v);
          float* cp = C + (size_t)row * N + col;
          if (RES) v += *cp;
          *cp = v;
        }
      }
    }
  }
}

// ------------------------------------------------------ flash attention fp32
// 16 queries/block x 16 lanes/query. Lane l owns dims {r*64 + l*4 + i}:
// conflict-free LDS reads (16 lanes -> 16 distinct bank quads, groups broadcast).
__global__ __launch_bounds__(256) void attn_kernel(const float* __restrict__ qkv,
                                                   float* __restrict__ o) {
  __shared__ float Ks[32][128];
  __shared__ float Vs[32][128];
  __shared__ float Sl[16][33];
  int bh = blockIdx.y;
  int b = bh >> 3, hh = bh & 7;
  int tid = threadIdx.x;
  int g = tid >> 4, l16 = tid & 15;
  int qi = blockIdx.x * 16 + g;
  bool qok = qi < S_LEN;
  const float* base = qkv + (size_t)b * S_LEN * 3072;
  float qv[8];
  if (qok) {
    float4 q0 = *(const float4*)(base + (size_t)qi * 3072 + hh * 128 + l16 * 4);
    float4 q1 = *(const float4*)(base + (size_t)qi * 3072 + hh * 128 + 64 + l16 * 4);
    qv[0] = q0.x; qv[1] = q0.y; qv[2] = q0.z; qv[3] = q0.w;
    qv[4] = q1.x; qv[5] = q1.y; qv[6] = q1.z; qv[7] = q1.w;
  } else {
#pragma unroll
    for (int j = 0; j < 8; ++j) qv[j] = 0.f;
  }
  float ov[8];
#pragma unroll
  for (int j = 0; j < 8; ++j) ov[j] = 0.f;
  float mrun = -INFINITY, lrun = 0.f;
  const float scale = 0.08838834764831845f;   // DHEAD**-0.5
  for (int j0 = 0; j0 < S_LEN; j0 += 32) {
    __syncthreads();
#pragma unroll
    for (int r = 0; r < 4; ++r) {
      int f4 = r * 256 + tid;
      int key = f4 >> 5;
      int c4 = (f4 & 31) * 4;
      int jj = j0 + key;
      float4 kv, vv;
      if (jj < S_LEN) {
        kv = *(const float4*)(base + (size_t)jj * 3072 + 1024 + hh * 128 + c4);
        vv = *(const float4*)(base + (size_t)jj * 3072 + 2048 + hh * 128 + c4);
      } else {
        kv = make_float4(0.f, 0.f, 0.f, 0.f);
        vv = make_float4(0.f, 0.f, 0.f, 0.f);
      }
      *(float4*)&Ks[key][c4] = kv;
      *(float4*)&Vs[key][c4] = vv;
    }
    __syncthreads();
    float tmax = -INFINITY;
    for (int jj = 0; jj < 32; ++jj) {
      float4 k0 = *(const float4*)&Ks[jj][l16 * 4];
      float4 k1 = *(const float4*)&Ks[jj][64 + l16 * 4];
      float s0 = qv[0] * k0.x; s0 = fmaf(qv[1], k0.y, s0);
      s0 = fmaf(qv[2], k0.z, s0); s0 = fmaf(qv[3], k0.w, s0);
      float s1 = qv[4] * k1.x; s1 = fmaf(qv[5], k1.y, s1);
      s1 = fmaf(qv[6], k1.z, s1); s1 = fmaf(qv[7], k1.w, s1);
      float s = s0 + s1;
      s += __shfl_xor(s, 1);
      s += __shfl_xor(s, 2);
      s += __shfl_xor(s, 4);
      s += __shfl_xor(s, 8);
      s *= scale;
      if (j0 + jj >= S_LEN) s = -INFINITY;
      if (l16 == (jj & 15)) Sl[g][jj] = s;
      tmax = fmaxf(tmax, s);
    }
    float mnew = fmaxf(mrun, tmax);
    float corr = expf(mrun - mnew);
    lrun *= corr;
#pragma unroll
    for (int j = 0; j < 8; ++j) ov[j] *= corr;
    for (int jj = 0; jj < 32; ++jj) {
      float p = expf(Sl[g][jj] - mnew);
      lrun += p;
      float4 v0 = *(const float4*)&Vs[jj][l16 * 4];
      float4 v1 = *(const float4*)&Vs[jj][64 + l16 * 4];
      ov[0] = fmaf(p, v0.x, ov[0]); ov[1] = fmaf(p, v0.y, ov[1]);
      ov[2] = fmaf(p, v0.z, ov[2]); ov[3] = fmaf(p, v0.w, ov[3]);
      ov[4] = fmaf(p, v1.x, ov[4]); ov[5] = fmaf(p, v1.y, ov[5]);
      ov[6] = fmaf(p, v1.z, ov[6]); ov[7] = fmaf(p, v1.w, ov[7]);
    }
    mrun = mnew;
  }
  if (qok) {
    float inv = 1.0f / lrun;
    float* op = o + ((size_t)(b * S_LEN + qi)) * 1024 + hh * 128;
    float4 o0, o1;
    o0.x = ov[0] * inv; o0.y = ov[1] * inv; o0.z = ov[2] * inv; o0.w = ov[3] * inv;
    o1.x = ov[4] * inv; o1.y = ov[5] * inv; o1.z = ov[6] * inv; o1.w = ov[7] * inv;
    *(float4*)(op + l16 * 4) = o0;
    *(float4*)(op + 64 + l16 * 4) = o1;
  }
}

// --------------------------------------------------- reduction head (j -> j64)
__global__ __launch_bounds__(256) void red_kernel(const float* __restrict__ x,
                                                  const float* __restrict__ lns,
                                                  const float* __restrict__ lnb,
                                                  const float* __restrict__ w1,
                                                  const float* __restrict__ b1,
                                                  const float* __restrict__ w2,
                                                  const float* __restrict__ b2,
                                                  float* __restrict__ j64) {
  __shared__ float row[1024];
  __shared__ float hid[512];
  __shared__ float red[8];
  int blk = blockIdx.x;
  int b = blk / 17, jj = blk % 17;
  int tid = threadIdx.x;
  float4 v = *(const float4*)(x + ((size_t)(b * 1041 + jj)) * 1024 + tid * 4);
  float sum = (v.x + v.y) + (v.z + v.w);
#pragma unroll
  for (int o = 32; o > 0; o >>= 1) sum += __shfl_xor(sum, o);
  if ((tid & 63) == 0) red[tid >> 6] = sum;
  __syncthreads();
  float mean = (red[0] + red[1] + red[2] + red[3]) * (1.0f / 1024.0f);
  float dx = v.x - mean, dy = v.y - mean, dz = v.z - mean, dw = v.w - mean;
  float sq = (dx * dx + dy * dy) + (dz * dz + dw * dw);
#pragma unroll
  for (int o = 32; o > 0; o >>= 1) sq += __shfl_xor(sq, o);
  if ((tid & 63) == 0) red[4 + (tid >> 6)] = sq;
  __syncthreads();
  float var = (red[4] + red[5] + red[6] + red[7]) * (1.0f / 1024.0f);
  float rs = rsqrtf(var + 1e-5f);
  float4 sv = *(const float4*)(lns + tid * 4);
  float4 bv = *(const float4*)(lnb + tid * 4);
  row[tid * 4 + 0] = dx * rs * sv.x + bv.x;
  row[tid * 4 + 1] = dy * rs * sv.y + bv.y;
  row[tid * 4 + 2] = dz * rs * sv.z + bv.z;
  row[tid * 4 + 3] = dw * rs * sv.w + bv.w;
  __syncthreads();
  for (int u = tid; u < 512; u += 256) {
    float acc = 0.f;
    for (int c = 0; c < 1024; ++c) acc = fmaf(row[c], w1[(size_t)c * 512 + u], acc);
    hid[u] = fmaxf(acc + b1[u], 0.f);
  }
  __syncthreads();
  if (tid < 64) {
    float acc = 0.f;
    for (int c = 0; c < 512; ++c) acc = fmaf(hid[c], w2[(size_t)c * 64 + tid], acc);
    j64[(size_t)blk * 64 + tid] = acc + b2[tid];
  }
}

// ------------------------------------------------------ final head (j64 -> 3)
__global__ __launch_bounds__(64) void head_kernel(const float* __restrict__ j64,
                                                  const float* __restrict__ lns,
                                                  const float* __restrict__ lnb,
                                                  const float* __restrict__ w1,
                                                  const float* __restrict__ b1,
                                                  const float* __restrict__ w2,
                                                  const float* __restrict__ b2,
                                                  float* __restrict__ outp) {
  __shared__ float nb[64];
  __shared__ float hid[32];
  int blk = blockIdx.x;
  int tid = threadIdx.x;
  float v = j64[(size_t)blk * 64 + tid];
  float sum = v;
#pragma unroll
  for (int o = 32; o > 0; o >>= 1) sum += __shfl_xor(sum, o);
  float mean = sum * (1.0f / 64.0f);
  float d = v - mean;
  float sq = d * d;
#pragma unroll
  for (int o = 32; o > 0; o >>= 1) sq += __shfl_xor(sq, o);
  float var = sq * (1.0f / 64.0f);
  float rs = rsqrtf(var + 1e-5f);
  nb[tid] = d * rs * lns[tid] + lnb[tid];
  __syncthreads();
  if (tid < 32) {
    float acc = 0.f;
    for (int c = 0; c < 64; ++c) acc = fmaf(nb[c], w1[c * 32 + tid], acc);
    hid[tid] = fmaxf(acc + b1[tid], 0.f);
  }
  __syncthreads();
  if (tid < 3) {
    float acc = 0.f;
    for (int c = 0; c < 32; ++c) acc = fmaf(hid[c], w2[c * 3 + tid], acc);
    outp[(size_t)blk * 3 + tid] = acc + b2[tid];
  }
}

extern "C" void kernel_launch(void* const* d_in, const int* in_sizes, int n_in,
                              void* d_out, int out_size, void* d_ws, size_t ws_size,
                              hipStream_t stream) {
  const float* radar = (const float*)d_in[0];
  const float* cdw   = (const float*)d_in[1];
  const float* cfw   = (const float*)d_in[2];
  const float* posw  = (const float*)d_in[3];
  const float* posb  = (const float*)d_in[4];
  const float* jt    = (const float*)d_in[5];
  const float* jp    = (const float*)d_in[6];
  const float* ln1s  = (const float*)d_in[7];
  const float* ln1b  = (const float*)d_in[8];
  const float* qkvw  = (const float*)d_in[9];
  const float* outw  = (const float*)d_in[10];
  const float* outb  = (const float*)d_in[11];
  const float* ln2s  = (const float*)d_in[12];
  const float* ln2b  = (const float*)d_in[13];
  const float* ffw1  = (const float*)d_in[14];
  const float* ffb1  = (const float*)d_in[15];
  const float* ffw2  = (const float*)d_in[16];
  const float* ffb2  = (const float*)d_in[17];
  const float* rlns  = (const float*)d_in[18];
  const float* rlnb  = (const float*)d_in[19];
  const float* rw1   = (const float*)d_in[20];
  const float* rb1   = (const float*)d_in[21];
  const float* rw2   = (const float*)d_in[22];
  const float* rb2   = (const float*)d_in[23];
  const float* hlns  = (const float*)d_in[24];
  const float* hlnb  = (const float*)d_in[25];
  const float* hw1   = (const float*)d_in[26];
  const float* hb1   = (const float*)d_in[27];
  const float* hw2   = (const float*)d_in[28];
  const float* hb2   = (const float*)d_in[29];

  // Output layout: out(102) | j64(2176) | features(2097152) | xyzts(8192)
  float* out0      = (float*)d_out;
  float* out_j64   = out0 + 102;
  float* out_feat  = out_j64 + 2176;
  float* out_xyzts = out_feat + 2097152;

  // Workspace: anchors | nidx | xbuf | hbuf | big | wbuf
  float* anchors = (float*)d_ws;                                  // 24 KB
  int*   nidx    = (int*)((char*)d_ws + 6144 * 4);                // 384 KB
  float* xbuf    = (float*)((char*)d_ws + (6144 + 98304) * 4);
  float* hbuf    = xbuf + (size_t)ROWS * 1024;
  float* big     = hbuf + (size_t)ROWS * 1024;
  unsigned short* wbuf = (unsigned short*)(big + (size_t)ROWS * 3072);  // 12.6 MB
  if (ws_size < 55640064u) return;

  fps_kernel<<<8, 256, 0, stream>>>(radar, anchors, out_xyzts);
  radius_kernel<<<24, 256, 0, stream>>>(radar, anchors, nidx);
  group_kernel<<<2048, 256, 0, stream>>>(radar, anchors, nidx, cdw, cfw, posw, posb,
                                         out_feat, xbuf);
  joints_kernel<<<34, 256, 0, stream>>>(jt, jp, xbuf);

  for (int l = 0; l < 5; ++l) {
    ln_kernel<<<ROWS, 256, 0, stream>>>(xbuf, ln1s + l * 1024, ln1b + l * 1024, hbuf);
    wconv<<<dim3(24, 32), 256, 0, stream>>>(qkvw + (size_t)l * 1024 * 3072, wbuf, 1024, 3072);
    mgemm<false, false, false><<<dim3(24, 17), 256, 0, stream>>>(
        hbuf, wbuf, nullptr, big, ROWS, 3072, 1024);
    attn_kernel<<<dim3(66, 16), 256, 0, stream>>>(big, hbuf);
    wconv<<<dim3(8, 32), 256, 0, stream>>>(outw + (size_t)l * 1024 * 1024, wbuf, 1024, 1024);
    mgemm<true, true, false><<<dim3(8, 17), 256, 0, stream>>>(
        hbuf, wbuf, outb + l * 1024, xbuf, ROWS, 1024, 1024);
    ln_kernel<<<ROWS, 256, 0, stream>>>(xbuf, ln2s + l * 1024, ln2b + l * 1024, hbuf);
    wconv<<<dim3(16, 32), 256, 0, stream>>>(ffw1 + (size_t)l * 1024 * 2048, wbuf, 1024, 2048);
    mgemm<true, false, true><<<dim3(16, 17), 256, 0, stream>>>(
        hbuf, wbuf, ffb1 + l * 2048, big, ROWS, 2048, 1024);
    wconv<<<dim3(8, 64), 256, 0, stream>>>(ffw2 + (size_t)l * 2048 * 1024, wbuf, 2048, 1024);
    mgemm<true, true, false><<<dim3(8, 17), 256, 0, stream>>>(
        big, wbuf, ffb2 + l * 1024, xbuf, ROWS, 1024, 2048);
  }

  red_kernel<<<34, 256, 0, stream>>>(xbuf, rlns, rlnb, rw1, rb1, rw2, rb2, out_j64);
  head_kernel<<<34, 64, 0, stream>>>(out_j64, hlns, hlnb, hw1, hb1, hw2, hb2, out0);
}